// Round 9
// baseline (215.877 us; speedup 1.0000x reference)
//
#include <hip/hip_runtime.h>

#define SEQ 4096
#define DM 1024
#define NH 16
#define DK 64

typedef _Float16 half8 __attribute__((ext_vector_type(8)));
typedef _Float16 half4v __attribute__((ext_vector_type(4)));
typedef float f32x4 __attribute__((ext_vector_type(4)));

#define MFMA16(a, b, c) __builtin_amdgcn_mfma_f32_16x16x32_f16((a), (b), (c), 0, 0, 0)
#define GLOAD_LDS(g, l)                                                                  \
    __builtin_amdgcn_global_load_lds((const __attribute__((address_space(1))) void*)(g), \
                                     (__attribute__((address_space(3))) void*)(l), 16, 0, 0)

// all-16-lane max via DPP (VALU pipe, ~5cyc/step) -- replaces 4-deep ds_bpermute chain
__device__ __forceinline__ float dpp_max16(float x) {
    x = fmaxf(x, __int_as_float(__builtin_amdgcn_update_dpp(
                     0, __float_as_int(x), 0xB1, 0xF, 0xF, true)));  // quad_perm xor1
    x = fmaxf(x, __int_as_float(__builtin_amdgcn_update_dpp(
                     0, __float_as_int(x), 0x4E, 0xF, 0xF, true)));  // quad_perm xor2
    x = fmaxf(x, __int_as_float(__builtin_amdgcn_update_dpp(
                     0, __float_as_int(x), 0x124, 0xF, 0xF, true)));  // row_ror:4
    x = fmaxf(x, __int_as_float(__builtin_amdgcn_update_dpp(
                     0, __float_as_int(x), 0x128, 0xF, 0xF, true)));  // row_ror:8
    return x;
}

__device__ __forceinline__ half8 cvt_f32x8(f32x4 lo, f32x4 hi) {
    half8 h;
    h[0] = (_Float16)lo[0]; h[1] = (_Float16)lo[1];
    h[2] = (_Float16)lo[2]; h[3] = (_Float16)lo[3];
    h[4] = (_Float16)hi[0]; h[5] = (_Float16)hi[1];
    h[6] = (_Float16)hi[2]; h[7] = (_Float16)hi[3];
    return h;
}

// ---------------- QKV projections: fused fp32->fp16, 128x128 tiles, BK=32 -------------
// R8 post-mortem: cvt_all (19us + ~10us launch slot) is pure pre-processing; its
// outputs feed ONLY the GEMMs. Fold the conversion into staging: global_load_lds the
// fp32 sources (A and B both fp32), convert at fragment-read. Same rounding path as
// the old pre-convert -> absmax identical. BK=32 keeps LDS at 32KB (3 blocks/CU) and
// the load count per step at 8 (bytes doubled, count constant).
// f32 rows stride 128B = 16-way conflict -> both-sides unit-XOR (rule 21, as attn Ks):
// source 16B-unit ^= row&7 at stage; read unit = (2*quad)^(l16&7). 8 units/2 lanes
// each = 2-way = free (m136).
__global__ void __launch_bounds__(256, 3) gemm_qkv(
    const float* __restrict__ q, const float* __restrict__ k, const float* __restrict__ v,
    const float* __restrict__ wq, const float* __restrict__ wk, const float* __restrict__ wv,
    const float* __restrict__ bq, const float* __restrict__ bk, const float* __restrict__ bv,
    _Float16* __restrict__ Qo, _Float16* __restrict__ Ko, _Float16* __restrict__ Vt) {
    __shared__ float As[128 * 32];  // 16KB, unit-swizzled fp32
    __shared__ float Bs[128 * 32];  // 16KB
    int z = blockIdx.z;
    const float *A, *B, *bias;
    float scale;
    if (z == 0) { A = q; B = wq; bias = bq; scale = 0.125f; }  // 1/sqrt(64)
    else if (z == 1) { A = k; B = wk; bias = bk; scale = 1.0f; }
    else { A = v; B = wv; bias = bv; scale = 1.0f; }

    const int m0 = blockIdx.x * 128;
    const int n0 = blockIdx.y * 128;
    const int tid = threadIdx.x;
    const int wave = tid >> 6, lane = tid & 63;
    const int quad = lane >> 4, l16 = lane & 15;
    const int wr = (wave >> 1) * 64;
    const int wc = (wave & 1) * 64;
    const int s7 = l16 & 7;

    f32x4 acc[4][4] = {};

    for (int k0 = 0; k0 < DM; k0 += 32) {
        // stage A,B fp32 tiles: 128 rows x 8 units(16B) = 1024 units each, 4/thread
#pragma unroll
        for (int i = 0; i < 4; ++i) {
            int U = i * 256 + tid;
            int row = U >> 3, u = U & 7;
            int c = k0 + ((u ^ (row & 7)) << 2);  // pre-swizzled source col (f32)
            GLOAD_LDS(A + (size_t)(m0 + row) * DM + c, As + U * 4);
            GLOAD_LDS(B + (size_t)(n0 + row) * DM + c, Bs + U * 4);
        }
        __syncthreads();

        half8 ah[4], bh[4];
        const int u0 = (2 * quad) ^ s7;
#pragma unroll
        for (int mi = 0; mi < 4; ++mi) {
            int row = wr + mi * 16 + l16;  // row&7 == l16&7
            f32x4 lo = *(const f32x4*)&As[row * 32 + u0 * 4];
            f32x4 hi = *(const f32x4*)&As[row * 32 + (u0 ^ 1) * 4];
            ah[mi] = cvt_f32x8(lo, hi);
        }
#pragma unroll
        for (int ni = 0; ni < 4; ++ni) {
            int row = wc + ni * 16 + l16;
            f32x4 lo = *(const f32x4*)&Bs[row * 32 + u0 * 4];
            f32x4 hi = *(const f32x4*)&Bs[row * 32 + (u0 ^ 1) * 4];
            bh[ni] = cvt_f32x8(lo, hi);
        }
#pragma unroll
        for (int mi = 0; mi < 4; ++mi)
#pragma unroll
            for (int ni = 0; ni < 4; ++ni)
                acc[mi][ni] = MFMA16(ah[mi], bh[ni], acc[mi][ni]);
        __syncthreads();
    }

    float bs[4];
#pragma unroll
    for (int ni = 0; ni < 4; ++ni) bs[ni] = bias[n0 + wc + ni * 16 + l16];

    if (z < 2) {
        _Float16* C = (z == 0) ? Qo : Ko;
#pragma unroll
        for (int mi = 0; mi < 4; ++mi)
#pragma unroll
            for (int ni = 0; ni < 4; ++ni) {
                int m = m0 + wr + mi * 16 + quad * 4;
                int n = n0 + wc + ni * 16 + l16;
#pragma unroll
                for (int r = 0; r < 4; ++r)
                    C[(size_t)(m + r) * DM + n] = (_Float16)((acc[mi][ni][r] + bs[ni]) * scale);
            }
    } else {
#pragma unroll
        for (int mi = 0; mi < 4; ++mi)
#pragma unroll
            for (int ni = 0; ni < 4; ++ni) {
                int m = m0 + wr + mi * 16 + quad * 4;
                int n = n0 + wc + ni * 16 + l16;
                half4v p;
#pragma unroll
                for (int r = 0; r < 4; ++r) p[r] = (_Float16)(acc[mi][ni][r] + bs[ni]);
                *(half4v*)(Vt + (size_t)n * SEQ + m) = p;  // m % 4 == 0 -> 8B aligned
            }
    }
}

// ---------------- output projection: A fp16 (Xh), B fp32 (wo), 64x128, BK=32 ----------
__global__ void __launch_bounds__(256, 3) gemm_out(const _Float16* __restrict__ Xh,
                                                   const float* __restrict__ wo,
                                                   const float* __restrict__ bo,
                                                   float* __restrict__ out) {
    __shared__ _Float16 As[64 * 32];  // 4KB, fp16, unit-swizzled (u ^= row&3)
    __shared__ float Bs[128 * 32];    // 16KB, fp32, unit-swizzled (u ^= row&7)
    const int m0 = blockIdx.x * 64;
    const int n0 = blockIdx.y * 128;
    const int tid = threadIdx.x;
    const int wave = tid >> 6, lane = tid & 63;
    const int quad = lane >> 4, l16 = lane & 15;
    const int wr = (wave >> 1) * 32;
    const int wc = (wave & 1) * 64;
    const int s7 = l16 & 7;

    f32x4 acc[2][4] = {};

    for (int k0 = 0; k0 < DM; k0 += 32) {
        // A: 64 rows x 4 units(16B, 8 halves) = 256 units, 1/thread
        {
            int row = tid >> 2, u = tid & 3;
            int c = k0 + ((u ^ (row & 3)) << 3);  // halves
            GLOAD_LDS(Xh + (size_t)(m0 + row) * DM + c, As + tid * 8);
        }
        // B: fp32, 128 rows x 8 units = 1024 units, 4/thread
#pragma unroll
        for (int i = 0; i < 4; ++i) {
            int U = i * 256 + tid;
            int row = U >> 3, u = U & 7;
            int c = k0 + ((u ^ (row & 7)) << 2);
            GLOAD_LDS(wo + (size_t)(n0 + row) * DM + c, Bs + U * 4);
        }
        __syncthreads();

        half8 ah[2], bh[4];
        const int ua = quad ^ (l16 & 3);
#pragma unroll
        for (int mi = 0; mi < 2; ++mi) {
            int row = wr + mi * 16 + l16;  // row&3 == l16&3
            ah[mi] = *(const half8*)&As[row * 32 + ua * 8];
        }
        const int u0 = (2 * quad) ^ s7;
#pragma unroll
        for (int ni = 0; ni < 4; ++ni) {
            int row = wc + ni * 16 + l16;
            f32x4 lo = *(const f32x4*)&Bs[row * 32 + u0 * 4];
            f32x4 hi = *(const f32x4*)&Bs[row * 32 + (u0 ^ 1) * 4];
            bh[ni] = cvt_f32x8(lo, hi);
        }
#pragma unroll
        for (int mi = 0; mi < 2; ++mi)
#pragma unroll
            for (int ni = 0; ni < 4; ++ni)
                acc[mi][ni] = MFMA16(ah[mi], bh[ni], acc[mi][ni]);
        __syncthreads();
    }

#pragma unroll
    for (int mi = 0; mi < 2; ++mi)
#pragma unroll
        for (int ni = 0; ni < 4; ++ni) {
            int m = m0 + wr + mi * 16 + quad * 4;
            int n = n0 + wc + ni * 16 + l16;
            float b = bo[n];
#pragma unroll
            for (int r = 0; r < 4; ++r) out[(size_t)(m + r) * DM + n] = acc[mi][ni][r] + b;
        }
}

// ---------------- windowed attention: K + V both LDS-staged (R8) ----------------------
// R4: bulk K staging (win). R8: V double-buffered via gload_lds, block-uniform union
// range; per-wave out-of-range tiles fully masked, self-heal via alpha=0 rescale.
// LDS = 40KB Ks + 5KB Pl + 8KB Vs = 53KB -> 3 blocks/CU.
__global__ void __launch_bounds__(256, 4) attn_kernel(const _Float16* __restrict__ Q,
                                                      const _Float16* __restrict__ K,
                                                      const _Float16* __restrict__ Vt,
                                                      _Float16* __restrict__ X) {
    __shared__ _Float16 Ks[320 * 64];   // 40KB, unit-swizzled (16B unit ^= row&7)
    __shared__ _Float16 Pl[4][16][40];  // 5KB, padded stride (80B, 16B-aligned rows)
    __shared__ _Float16 Vs[2][64][32];  // 8KB, dbuf: [d-row][32 keys of tile]
    int tid = threadIdx.x;
    int wave = tid >> 6, lane = tid & 63;
    int quad = lane >> 4, l16 = lane & 15;
    int h = blockIdx.y;
    int bx = ((blockIdx.x & 7) << 3) + (blockIdx.x >> 3);  // XCD-contiguous q-spans
    int q0b = bx * 64;
    int q0 = q0b + wave * 16;
    int kspan0 = q0b - 128;

    // ---- bulk K staging: 320 rows x 8 units(16B) = 2560 units, 10 per thread --------
    const _Float16* Kg = K + h * DK;
#pragma unroll
    for (int i = 0; i < 10; ++i) {
        int U = i * 256 + tid;        // linear 16B-unit index in LDS
        int row = U >> 3, u = U & 7;  // rel row, unit-in-row
        int rg = kspan0 + row;
        rg = rg < 0 ? 0 : (rg > SEQ - 1 ? SEQ - 1 : rg);  // clamp: garbage rows are
                                                          // always window-masked
        GLOAD_LDS(Kg + (size_t)rg * DM + ((u ^ (row & 7)) << 3), Ks + U * 8);
    }

    // block-uniform tile range (union of all 4 waves' windows; all kt in [0, SEQ-32])
    int ustart = (q0b > 127) ? (q0b - 128) : 0;
    int uend = q0b + 191;
    if (uend > SEQ - 1) uend = SEQ - 1;
    int nt = ((uend - ustart) >> 5) + 1;

    // ---- V staging: tile = 64 d-rows x 32 keys = 4KB = 1 gload_lds/thread ------------
    const _Float16* Vg = Vt + (size_t)(h * DK) * SEQ;
    const int vdd = tid >> 2, vu = (tid & 3) * 8;  // d-row, key-offset(halves)
    GLOAD_LDS(Vg + (size_t)vdd * SEQ + ustart + vu, (_Float16*)Vs + tid * 8);  // V[0]

    const _Float16* Qp = Q + (size_t)(q0 + l16) * DM + h * DK + quad * 8;
    half8 aq0 = *(const half8*)(Qp);
    half8 aq1 = *(const half8*)(Qp + 32);
    const half8 ones = {(_Float16)1, (_Float16)1, (_Float16)1, (_Float16)1,
                        (_Float16)1, (_Float16)1, (_Float16)1, (_Float16)1};

    float rowM[4], rowL[4];
    f32x4 o[4] = {};
#pragma unroll
    for (int r = 0; r < 4; ++r) { rowM[r] = -__builtin_inff(); rowL[r] = 0.f; }

    const int xk = l16 & 7;

    __syncthreads();  // Ks + V[0] staging complete (drains vmcnt)

    for (int i = 0; i < nt; ++i) {
        int kt = ustart + i * 32;
        int buf = i & 1;
        if (i > 0) {
            // V[i]'s single load (issued last iter) landed; all waves past iter i-1
            asm volatile("s_waitcnt vmcnt(0)" ::: "memory");
            asm volatile("s_barrier" ::: "memory");
        }
        // stage V[i+1] into buf^1 -- WAR-safe: barrier above proves iter i-1's readers done
        if (i + 1 < nt)
            GLOAD_LDS(Vg + (size_t)vdd * SEQ + (kt + 32) + vu,
                      (_Float16*)Vs + (buf ^ 1) * 2048 + tid * 8);

        // QK^T from LDS K (swizzled read: row&7 == l16&7 since rel%32==0)
        int rel = kt - kspan0;  // in [0, 320), multiple of 32
        f32x4 s[2];
#pragma unroll
        for (int cf = 0; cf < 2; ++cf) {
            int rr = rel + cf * 16 + l16;
            half8 b0 = *(const half8*)&Ks[rr * 64 + ((quad ^ xk) << 3)];
            half8 b1 = *(const half8*)&Ks[rr * 64 + (((quad + 4) ^ xk) << 3)];
            f32x4 z = {};
            z = MFMA16(aq0, b0, z);
            z = MFMA16(aq1, b1, z);
            s[cf] = z;
        }
        // wave-uniform: tile fully inside every row's window?
        const bool full = (kt >= q0 - 112) && (kt <= q0 + 97);
        float alpha[4];
#pragma unroll
        for (int r = 0; r < 4; ++r) {
            float x0 = s[0][r], x1 = s[1][r];
            if (!full) {
                int row = q0 + quad * 4 + r;
                int key0 = kt + l16, key1 = kt + 16 + l16;
                if (key0 < row - 127 || key0 > row + 128) x0 = -1e30f;
                if (key1 < row - 127 || key1 > row + 128) x1 = -1e30f;
            }
            float t = dpp_max16(fmaxf(x0, x1));
            float mnew = fmaxf(rowM[r], t);
            alpha[r] = __expf(rowM[r] - mnew);  // first/poison tile: exp(-inf..)=0 wipes
            float p0 = __expf(x0 - mnew);
            float p1 = __expf(x1 - mnew);
            Pl[wave][quad * 4 + r][l16] = (_Float16)p0;
            Pl[wave][quad * 4 + r][l16 + 16] = (_Float16)p1;
            rowM[r] = mnew;
        }
        // P: C-layout -> A-operand layout via per-wave LDS round-trip (wave-internal)
        half8 ap = *(const half8*)&Pl[wave][l16][quad * 8];
        f32x4 ts = {};
        ts = MFMA16(ap, ones, ts);  // ts[r] = this tile's row sum (all cols identical)
#pragma unroll
        for (int r = 0; r < 4; ++r) rowL[r] = rowL[r] * alpha[r] + ts[r];
#pragma unroll
        for (int ni = 0; ni < 4; ++ni) {
#pragma unroll
            for (int r = 0; r < 4; ++r) o[ni][r] *= alpha[r];
            half8 bv = *(const half8*)&Vs[buf][ni * 16 + l16][quad * 8];
            o[ni] = MFMA16(ap, bv, o[ni]);
        }
    }

    float rinv[4];
#pragma unroll
    for (int r = 0; r < 4; ++r) rinv[r] = 1.0f / rowL[r];
#pragma unroll
    for (int ni = 0; ni < 4; ++ni) {
        int n = h * DK + ni * 16 + l16;
#pragma unroll
        for (int r = 0; r < 4; ++r) {
            int m = q0 + quad * 4 + r;
            X[(size_t)m * DM + n] = (_Float16)(o[ni][r] * rinv[r]);
        }
    }
}

extern "C" void kernel_launch(void* const* d_in, const int* in_sizes, int n_in, void* d_out,
                              int out_size, void* d_ws, size_t ws_size, hipStream_t stream) {
    const float* q  = (const float*)d_in[0];
    const float* k  = (const float*)d_in[1];
    const float* v  = (const float*)d_in[2];
    const float* wq = (const float*)d_in[3];
    const float* bq = (const float*)d_in[4];
    const float* wk = (const float*)d_in[5];
    const float* bk = (const float*)d_in[6];
    const float* wv = (const float*)d_in[7];
    const float* bv = (const float*)d_in[8];
    const float* wo = (const float*)d_in[9];
    const float* bo = (const float*)d_in[10];

    const size_t SZ_T = (size_t)SEQ * DM * sizeof(_Float16);  // 8 MB
    char* p = (char*)d_ws;
    _Float16* Qo = (_Float16*)(p);
    _Float16* Ko = (_Float16*)(p + SZ_T);
    _Float16* Vt = (_Float16*)(p + 2 * SZ_T);
    _Float16* Xh = (_Float16*)(p + 3 * SZ_T);

    gemm_qkv<<<dim3(32, 8, 3), 256, 0, stream>>>(q, k, v, wq, wk, wv, bq, bk, bv, Qo, Ko, Vt);
    attn_kernel<<<dim3(SEQ / 64, NH), 256, 0, stream>>>(Qo, Ko, Vt, Xh);
    gemm_out<<<dim3(64, 8), 256, 0, stream>>>(Xh, wo, bo, (float*)d_out);
}

// Round 10
// 191.438 us; speedup vs baseline: 1.1277x; 1.1277x over previous
//
#include <hip/hip_runtime.h>

#define SEQ 4096
#define DM 1024
#define NH 16
#define DK 64

typedef _Float16 half8 __attribute__((ext_vector_type(8)));
typedef _Float16 half4v __attribute__((ext_vector_type(4)));
typedef float f32x4 __attribute__((ext_vector_type(4)));

#define MFMA16(a, b, c) __builtin_amdgcn_mfma_f32_16x16x32_f16((a), (b), (c), 0, 0, 0)
#define GLOAD_LDS(g, l)                                                                  \
    __builtin_amdgcn_global_load_lds((const __attribute__((address_space(1))) void*)(g), \
                                     (__attribute__((address_space(3))) void*)(l), 16, 0, 0)

// all-16-lane max via DPP (VALU pipe, ~5cyc/step) -- replaces 4-deep ds_bpermute chain
__device__ __forceinline__ float dpp_max16(float x) {
    x = fmaxf(x, __int_as_float(__builtin_amdgcn_update_dpp(
                     0, __float_as_int(x), 0xB1, 0xF, 0xF, true)));  // quad_perm xor1
    x = fmaxf(x, __int_as_float(__builtin_amdgcn_update_dpp(
                     0, __float_as_int(x), 0x4E, 0xF, 0xF, true)));  // quad_perm xor2
    x = fmaxf(x, __int_as_float(__builtin_amdgcn_update_dpp(
                     0, __float_as_int(x), 0x124, 0xF, 0xF, true)));  // row_ror:4
    x = fmaxf(x, __int_as_float(__builtin_amdgcn_update_dpp(
                     0, __float_as_int(x), 0x128, 0xF, 0xF, true)));  // row_ror:8
    return x;
}

// ---------------- fp32 -> fp16 conversion (7 tensors in one launch, 16B stores) --------
// R9 post-mortem: fusing this into the GEMMs doubled their staged bytes through the
// global->LDS path (the GEMMs' binding constraint) -- qkv 40->78us. Standalone cvt at
// ~19us (80% HBM eff) is the cheaper way to pay for precision conversion. Keep it.
__global__ void cvt_all(const float* __restrict__ q, const float* __restrict__ k,
                        const float* __restrict__ v, const float* __restrict__ wq,
                        const float* __restrict__ wk, const float* __restrict__ wv,
                        const float* __restrict__ wo, _Float16* __restrict__ qh,
                        _Float16* __restrict__ kh, _Float16* __restrict__ vh,
                        _Float16* __restrict__ wqh, _Float16* __restrict__ wkh,
                        _Float16* __restrict__ wvh, _Float16* __restrict__ woh) {
    int z = blockIdx.y;
    const float* src;
    _Float16* dst;
    int n;
    switch (z) {
    case 0: src = q;  dst = qh;  n = SEQ * DM; break;
    case 1: src = k;  dst = kh;  n = SEQ * DM; break;
    case 2: src = v;  dst = vh;  n = SEQ * DM; break;
    case 3: src = wq; dst = wqh; n = DM * DM;  break;
    case 4: src = wk; dst = wkh; n = DM * DM;  break;
    case 5: src = wv; dst = wvh; n = DM * DM;  break;
    default: src = wo; dst = woh; n = DM * DM; break;
    }
    int idx = (blockIdx.x * 256 + threadIdx.x) * 8;
    if (idx >= n) return;
    float4 f0 = *(const float4*)(src + idx);
    float4 f1 = *(const float4*)(src + idx + 4);
    half8 h;
    h[0] = (_Float16)f0.x; h[1] = (_Float16)f0.y; h[2] = (_Float16)f0.z; h[3] = (_Float16)f0.w;
    h[4] = (_Float16)f1.x; h[5] = (_Float16)f1.y; h[6] = (_Float16)f1.z; h[7] = (_Float16)f1.w;
    *(half8*)(dst + idx) = h;
}

// ---------------- m97-structure f16 GEMM, BK=64 (R4 config: best measured, 40.2us) -----
// R5/R6/R7/R9 post-mortem: dbuf+syncthreads, counted-vmcnt, 256^2 tiles, and fused-fp32
// staging all regress or tie -- the kernel sits on the global->LDS delivery-path floor.
// This single-buffer BK=64 fp16 form is the best-measured config. Do not touch.
template <int MT>  // M-tile: 128 (qkv) or 64 (out); N-tile fixed 128
__device__ __forceinline__ void gemm_bk64(const _Float16* __restrict__ A,
                                          const _Float16* __restrict__ B, int m0, int n0,
                                          _Float16* As, _Float16* Bs, f32x4 (*acc)[4]) {
    constexpr int MI = MT / 32;
    constexpr int ACH = MT / 64;
    const int tid = threadIdx.x;
    const int wave = tid >> 6, lane = tid & 63;
    const int quad = lane >> 4, l16 = lane & 15;
    const int wr = (wave >> 1) * (MT / 2);
    const int wc = (wave & 1) * 64;
    const int srow = tid >> 2, scol = (tid & 3) * 8;

    for (int k0 = 0; k0 < DM; k0 += 64) {
#pragma unroll
        for (int p = 0; p < 2; ++p) {
            int kc = k0 + p * 32 + scol;
#pragma unroll
            for (int j = 0; j < ACH; ++j)
                GLOAD_LDS(A + (size_t)(m0 + j * 64 + srow) * DM + kc,
                          As + p * (MT * 32) + j * 2048 + tid * 8);
#pragma unroll
            for (int j = 0; j < 2; ++j)
                GLOAD_LDS(B + (size_t)(n0 + j * 64 + srow) * DM + kc,
                          Bs + p * 4096 + j * 2048 + tid * 8);
        }
        __syncthreads();
#pragma unroll
        for (int p = 0; p < 2; ++p) {
            half8 af[MI], bf[4];
#pragma unroll
            for (int mi = 0; mi < MI; ++mi)
                af[mi] = *(const half8*)&As[p * (MT * 32) + (wr + mi * 16 + l16) * 32 + quad * 8];
#pragma unroll
            for (int ni = 0; ni < 4; ++ni)
                bf[ni] = *(const half8*)&Bs[p * 4096 + (wc + ni * 16 + l16) * 32 + quad * 8];
#pragma unroll
            for (int mi = 0; mi < MI; ++mi)
#pragma unroll
                for (int ni = 0; ni < 4; ++ni)
                    acc[mi][ni] = MFMA16(af[mi], bf[ni], acc[mi][ni]);
        }
        __syncthreads();
    }
}

// ---------------- QKV projections: 128x128 tiles, grid (32,8,3) = 3 blocks/CU ----------
__global__ void __launch_bounds__(256, 3) gemm_qkv(
    const _Float16* __restrict__ qh, const _Float16* __restrict__ kh,
    const _Float16* __restrict__ vh, const _Float16* __restrict__ wqh,
    const _Float16* __restrict__ wkh, const _Float16* __restrict__ wvh,
    const float* __restrict__ bq, const float* __restrict__ bk, const float* __restrict__ bv,
    _Float16* __restrict__ Qo, _Float16* __restrict__ Ko, _Float16* __restrict__ Vt) {
    __shared__ _Float16 As[2 * 128 * 32];
    __shared__ _Float16 Bs[2 * 128 * 32];
    int z = blockIdx.z;
    const _Float16 *A, *B;
    const float* bias;
    float scale;
    if (z == 0) { A = qh; B = wqh; bias = bq; scale = 0.125f; }  // 1/sqrt(64)
    else if (z == 1) { A = kh; B = wkh; bias = bk; scale = 1.0f; }
    else { A = vh; B = wvh; bias = bv; scale = 1.0f; }

    int m0 = blockIdx.x * 128;
    int n0 = blockIdx.y * 128;
    f32x4 acc[4][4] = {};
    gemm_bk64<128>(A, B, m0, n0, As, Bs, acc);

    const int tid = threadIdx.x;
    const int wave = tid >> 6, lane = tid & 63;
    const int quad = lane >> 4, l16 = lane & 15;
    const int wr = (wave >> 1) * 64;
    const int wc = (wave & 1) * 64;
    float bs[4];
#pragma unroll
    for (int ni = 0; ni < 4; ++ni) bs[ni] = bias[n0 + wc + ni * 16 + l16];

    if (z < 2) {
        _Float16* C = (z == 0) ? Qo : Ko;
#pragma unroll
        for (int mi = 0; mi < 4; ++mi)
#pragma unroll
            for (int ni = 0; ni < 4; ++ni) {
                int m = m0 + wr + mi * 16 + quad * 4;
                int n = n0 + wc + ni * 16 + l16;
#pragma unroll
                for (int r = 0; r < 4; ++r)
                    C[(size_t)(m + r) * DM + n] = (_Float16)((acc[mi][ni][r] + bs[ni]) * scale);
            }
    } else {
#pragma unroll
        for (int mi = 0; mi < 4; ++mi)
#pragma unroll
            for (int ni = 0; ni < 4; ++ni) {
                int m = m0 + wr + mi * 16 + quad * 4;
                int n = n0 + wc + ni * 16 + l16;
                half4v p;
#pragma unroll
                for (int r = 0; r < 4; ++r) p[r] = (_Float16)(acc[mi][ni][r] + bs[ni]);
                *(half4v*)(Vt + (size_t)n * SEQ + m) = p;  // m % 4 == 0 -> 8B aligned
            }
    }
}

// ---------------- output projection: 64x128 tiles, grid (64,8) ------------------------
__global__ void __launch_bounds__(256, 3) gemm_out(const _Float16* __restrict__ Xh,
                                                   const _Float16* __restrict__ woh,
                                                   const float* __restrict__ bo,
                                                   float* __restrict__ out) {
    __shared__ _Float16 As[2 * 64 * 32];
    __shared__ _Float16 Bs[2 * 128 * 32];
    int m0 = blockIdx.x * 64;
    int n0 = blockIdx.y * 128;
    f32x4 acc[2][4] = {};
    gemm_bk64<64>(Xh, woh, m0, n0, As, Bs, acc);

    const int tid = threadIdx.x;
    const int wave = tid >> 6, lane = tid & 63;
    const int quad = lane >> 4, l16 = lane & 15;
    const int wr = (wave >> 1) * 32;
    const int wc = (wave & 1) * 64;
#pragma unroll
    for (int mi = 0; mi < 2; ++mi)
#pragma unroll
        for (int ni = 0; ni < 4; ++ni) {
            int m = m0 + wr + mi * 16 + quad * 4;
            int n = n0 + wc + ni * 16 + l16;
            float b = bo[n];
#pragma unroll
            for (int r = 0; r < 4; ++r) out[(size_t)(m + r) * DM + n] = acc[mi][ni][r] + b;
        }
}

// ---------------- windowed attention: 128 queries/block, 8 waves, bulk K in LDS -------
// R4 (win): bulk K staging removed the per-tile load serialization. This round scales
// the SAME per-wave inner loop to 128-query blocks (8 waves x 16 q, 512 thr):
//   - K window [q0b-128, q0b+256) = 384 rows = 48KB -> staged bytes PER QUERY halve
//     (24.6MB vs 41MB chip-wide).
//   - LDS 48+10 = 58KB -> 2 blocks/CU -> 16 waves/CU (4/SIMD) vs 12: more chains to
//     interleave on the latency-bound softmax path.
//   - V stays global per-tile (R8's V-staging measured ~= global; global avoids the
//     block-uniform union waste at 128-q granularity).
// launch_bounds(512,2) -> 128-VGPR cap; per-wave state ~48-64 regs (R4-measured), safe.
__global__ void __launch_bounds__(512, 2) attn_kernel(const _Float16* __restrict__ Q,
                                                      const _Float16* __restrict__ K,
                                                      const _Float16* __restrict__ Vt,
                                                      _Float16* __restrict__ X) {
    __shared__ _Float16 Ks[384 * 64];   // 48KB, unit-swizzled (16B unit ^= row&7)
    __shared__ _Float16 Pl[8][16][40];  // 10KB, padded stride
    int tid = threadIdx.x;
    int wave = tid >> 6, lane = tid & 63;
    int quad = lane >> 4, l16 = lane & 15;
    int h = blockIdx.y;
    int bx = ((blockIdx.x & 7) << 2) + (blockIdx.x >> 3);  // 32 blocks -> 8 XCD chunks of 4
    int q0b = bx * 128;
    int q0 = q0b + wave * 16;
    int kspan0 = q0b - 128;

    // ---- bulk K staging: 384 rows x 8 units(16B) = 3072 units, 6 per thread ----------
    const _Float16* Kg = K + h * DK;
#pragma unroll
    for (int i = 0; i < 6; ++i) {
        int U = i * 512 + tid;        // linear 16B-unit index in LDS
        int row = U >> 3, u = U & 7;  // rel row, unit-in-row
        int rg = kspan0 + row;
        rg = rg < 0 ? 0 : (rg > SEQ - 1 ? SEQ - 1 : rg);  // clamp: garbage rows are
                                                          // always window-masked
        GLOAD_LDS(Kg + (size_t)rg * DM + ((u ^ (row & 7)) << 3), Ks + U * 8);
    }

    const _Float16* Qp = Q + (size_t)(q0 + l16) * DM + h * DK + quad * 8;
    half8 aq0 = *(const half8*)(Qp);
    half8 aq1 = *(const half8*)(Qp + 32);
    const half8 ones = {(_Float16)1, (_Float16)1, (_Float16)1, (_Float16)1,
                        (_Float16)1, (_Float16)1, (_Float16)1, (_Float16)1};

    float rowM[4], rowL[4];
    f32x4 o[4] = {};
#pragma unroll
    for (int r = 0; r < 4; ++r) { rowM[r] = -__builtin_inff(); rowL[r] = 0.f; }

    int kstart = (q0 > 127) ? ((q0 - 127) & ~31) : 0;
    int kend = q0 + 143;
    if (kend > SEQ - 1) kend = SEQ - 1;
    const int xk = l16 & 7;

    __syncthreads();  // staging complete (barrier drains vmcnt)

    for (int kt = kstart; kt <= kend; kt += 32) {
        int rel = kt - kspan0;  // in [0, 384), multiple of 32
        // V loads for this tile -- consumed at the PV MFMAs ~700cyc later
        half8 vb[4];
#pragma unroll
        for (int ni = 0; ni < 4; ++ni)
            vb[ni] = *(const half8*)(Vt + (size_t)(h * DK + ni * 16 + l16) * SEQ + kt + quad * 8);

        // QK^T from LDS K (swizzled read: rr&7 == l16&7 since rel%32==0)
        f32x4 s[2];
#pragma unroll
        for (int cf = 0; cf < 2; ++cf) {
            int rr = rel + cf * 16 + l16;
            half8 b0 = *(const half8*)&Ks[rr * 64 + ((quad ^ xk) << 3)];
            half8 b1 = *(const half8*)&Ks[rr * 64 + (((quad + 4) ^ xk) << 3)];
            f32x4 z = {};
            z = MFMA16(aq0, b0, z);
            z = MFMA16(aq1, b1, z);
            s[cf] = z;
        }
        // wave-uniform: tile fully inside every row's window?
        const bool full = (kt >= q0 - 112) && (kt <= q0 + 97);
        float alpha[4];
#pragma unroll
        for (int r = 0; r < 4; ++r) {
            float x0 = s[0][r], x1 = s[1][r];
            if (!full) {
                int row = q0 + quad * 4 + r;
                int key0 = kt + l16, key1 = kt + 16 + l16;
                if (key0 < row - 127 || key0 > row + 128) x0 = -1e30f;
                if (key1 < row - 127 || key1 > row + 128) x1 = -1e30f;
            }
            float t = dpp_max16(fmaxf(x0, x1));
            float mnew = fmaxf(rowM[r], t);
            alpha[r] = __expf(rowM[r] - mnew);  // first tile: exp(-inf - finite) = 0
            float p0 = __expf(x0 - mnew);
            float p1 = __expf(x1 - mnew);
            Pl[wave][quad * 4 + r][l16] = (_Float16)p0;
            Pl[wave][quad * 4 + r][l16 + 16] = (_Float16)p1;
            rowM[r] = mnew;
        }
        // P: C-layout -> A-operand layout via per-wave LDS round-trip (wave-internal)
        half8 ap = *(const half8*)&Pl[wave][l16][quad * 8];
        f32x4 ts = {};
        ts = MFMA16(ap, ones, ts);  // ts[r] = this tile's row sum (all cols identical)
#pragma unroll
        for (int r = 0; r < 4; ++r) rowL[r] = rowL[r] * alpha[r] + ts[r];
#pragma unroll
        for (int ni = 0; ni < 4; ++ni) {
#pragma unroll
            for (int r = 0; r < 4; ++r) o[ni][r] *= alpha[r];
            o[ni] = MFMA16(ap, vb[ni], o[ni]);
        }
    }

    float rinv[4];
#pragma unroll
    for (int r = 0; r < 4; ++r) rinv[r] = 1.0f / rowL[r];
#pragma unroll
    for (int ni = 0; ni < 4; ++ni) {
        int n = h * DK + ni * 16 + l16;
#pragma unroll
        for (int r = 0; r < 4; ++r) {
            int m = q0 + quad * 4 + r;
            X[(size_t)m * DM + n] = (_Float16)(o[ni][r] * rinv[r]);
        }
    }
}

extern "C" void kernel_launch(void* const* d_in, const int* in_sizes, int n_in, void* d_out,
                              int out_size, void* d_ws, size_t ws_size, hipStream_t stream) {
    const float* q  = (const float*)d_in[0];
    const float* k  = (const float*)d_in[1];
    const float* v  = (const float*)d_in[2];
    const float* wq = (const float*)d_in[3];
    const float* bq = (const float*)d_in[4];
    const float* wk = (const float*)d_in[5];
    const float* bk = (const float*)d_in[6];
    const float* wv = (const float*)d_in[7];
    const float* bv = (const float*)d_in[8];
    const float* wo = (const float*)d_in[9];
    const float* bo = (const float*)d_in[10];

    const size_t SZ_T = (size_t)SEQ * DM * sizeof(_Float16);  // 8 MB
    const size_t SZ_W = (size_t)DM * DM * sizeof(_Float16);   // 2 MB
    char* p = (char*)d_ws;
    _Float16* qh  = (_Float16*)(p);
    _Float16* kh  = (_Float16*)(p + SZ_T);
    _Float16* vh  = (_Float16*)(p + 2 * SZ_T);
    _Float16* wqh = (_Float16*)(p + 3 * SZ_T);
    _Float16* wkh = (_Float16*)(p + 3 * SZ_T + SZ_W);
    _Float16* wvh = (_Float16*)(p + 3 * SZ_T + 2 * SZ_W);
    _Float16* woh = (_Float16*)(p + 3 * SZ_T + 3 * SZ_W);
    _Float16* Qo  = (_Float16*)(p + 3 * SZ_T + 4 * SZ_W);
    _Float16* Ko  = (_Float16*)(p + 4 * SZ_T + 4 * SZ_W);
    _Float16* Vt  = (_Float16*)(p + 5 * SZ_T + 4 * SZ_W);
    _Float16* Xh  = qh;  // alias: qh dead after gemm_qkv (stream-serialized)

    cvt_all<<<dim3(2048, 7), 256, 0, stream>>>(q, k, v, wq, wk, wv, wo, qh, kh, vh, wqh, wkh,
                                               wvh, woh);
    gemm_qkv<<<dim3(32, 8, 3), 256, 0, stream>>>(qh, kh, vh, wqh, wkh, wvh, bq, bk, bv, Qo, Ko,
                                                 Vt);
    attn_kernel<<<dim3(SEQ / 128, NH), 512, 0, stream>>>(Qo, Ko, Vt, Xh);
    gemm_out<<<dim3(64, 8), 256, 0, stream>>>(Xh, woh, bo, (float*)d_out);
}